// Round 5
// baseline (1714.333 us; speedup 1.0000x reference)
//
#include <hip/hip_runtime.h>

// SNN recurrence, B=64 T=256 F=1024 fp32. 256 persistent WGs (1 per CU,
// forced by 144KB LDS): js = bid>>2 (16 output cols), bg = bid&3 (16 batch
// rows; bg's 64 WGs sit on 2 XCDs). W column-slice in LDS as 4 signed
// base-512 digit limbs (exact in bf16); spk@W.T = 4 bf16 MFMAs per K-chunk
// with EXACT integer fp32 accumulation; limbs recombine in fp64; syn/mem fp64.
//
// Fence-free tagged-word exchange: word = ((t+1)<<16)|16 spike bits, relaxed
// agent-scope stores/loads. Bitmap layout makes each consumer lane's 4 A-frag
// words contiguous: the poll loads ARE the MFMA input. ONE barrier per step
// (LDS-only: inline s_waitcnt lgkmcnt(0)+s_barrier — no vmcnt drain, so
// output stores and x prefetch never gate the recurrence chain). partD WAR
// across steps is protected by the publish gate: a wave can only see tag t+1
// from its OWN WG (gate word, rows 0..3) after all 4 publisher waves posted
// step t, which data-depends on their partD reads at t. 4-deep slot ring
// (64KB ws), memset per launch (replay-safe).

#define NT 512

typedef __bf16 bf16x8 __attribute__((ext_vector_type(8)));
typedef float f32x4 __attribute__((ext_vector_type(4)));
typedef int i32x4 __attribute__((ext_vector_type(4)));

static __device__ __forceinline__ unsigned short f2bf(float v) {
    union { float f; unsigned int u; } a; a.f = v;
    unsigned int u = a.u;
    u += 0x7fffu + ((u >> 16) & 1u);   // RNE (exact for small ints)
    return (unsigned short)(u >> 16);
}

// 4 signed base-512 digits of round(w * 2^36); digits in [-256,255], exact in bf16.
static __device__ __forceinline__ void decomp512(float w, int* d) {
    long long v = llround((double)w * 68719476736.0);  // 2^36
    #pragma unroll
    for (int i = 0; i < 4; ++i) {
        int r = (int)(v & 511);
        if (r >= 256) r -= 512;
        d[i] = r;
        v = (v - (long long)r) >> 9;
    }
}

__launch_bounds__(NT, 1)
__global__ void snn_persist_kernel(const float* __restrict__ x,
                                   const float* __restrict__ W,
                                   const float* __restrict__ bias,
                                   float* __restrict__ out,
                                   unsigned int* __restrict__ gbm)
{
    constexpr int T = 256, F = 1024;
    const int bid = blockIdx.x;
    const int bg  = bid & 3;    // batch group: rows bg*16..+15
    const int js  = bid >> 2;   // j-slice: cols js*16..+15
    const int tid = threadIdx.x;
    const int lane = tid & 63;
    const int wv   = tid >> 6;  // wave 0..7 (K-split: chunks wv*4..wv*4+3)
    const int q = lane >> 4, r15 = lane & 15;
    const int qh = q >> 1, ql = q & 1;

    // W digit slices, MFMA B-operand order: [kc 0..31][lane 0..63][8 bf16]
    __shared__ __align__(16) unsigned int wd0[32*64*4];
    __shared__ __align__(16) unsigned int wd1[32*64*4];
    __shared__ __align__(16) unsigned int wd2[32*64*4];
    __shared__ __align__(16) unsigned int wd3[32*64*4];
    __shared__ double partD[8*256];   // per-wave limb-recombined partial h
    // total LDS = 128KB + 16KB = 144KB -> exactly 1 WG/CU (160KB limit)

    // ---- init: load W slice, 4-digit split, store in fragment order ----
    // B-frag: lane l supplies B[k=(l>>4)*8+i][n=l&15]; global W[js*16+n][kc*32+(l>>4)*8+i]
    for (int it = 0; it < 4; ++it) {
        int s = tid + NT*it;            // slot 0..2047 = (kc,l)
        int kc = s >> 6, l = s & 63;
        int n = l & 15, qq = l >> 4;
        int f0 = kc*32 + qq*8;
        const float* wr = W + (size_t)(js*16 + n)*F + f0;
        float e[8];
        *(float4*)&e[0] = *(const float4*)(wr);
        *(float4*)&e[4] = *(const float4*)(wr + 4);
        unsigned int pk0[4], pk1[4], pk2[4], pk3[4];
        #pragma unroll
        for (int i = 0; i < 4; ++i) {
            int da[4], db[4];
            decomp512(e[2*i],   da);
            decomp512(e[2*i+1], db);
            pk0[i] = (unsigned int)f2bf((float)da[0]) | ((unsigned int)f2bf((float)db[0]) << 16);
            pk1[i] = (unsigned int)f2bf((float)da[1]) | ((unsigned int)f2bf((float)db[1]) << 16);
            pk2[i] = (unsigned int)f2bf((float)da[2]) | ((unsigned int)f2bf((float)db[2]) << 16);
            pk3[i] = (unsigned int)f2bf((float)da[3]) | ((unsigned int)f2bf((float)db[3]) << 16);
        }
        #pragma unroll
        for (int i = 0; i < 4; ++i) {
            wd0[s*4+i] = pk0[i]; wd1[s*4+i] = pk1[i];
            wd2[s*4+i] = pk2[i]; wd3[s*4+i] = pk3[i];
        }
    }

    // state mapping (tid<256), matching MFMA C layout after the LDS reduce:
    // row b = ((tid>>4)&3)*4 + (tid>>6), col j = tid&15
    const int brow = ((tid >> 4) & 3)*4 + (tid >> 6);
    const int jcol = tid & 15;
    const int bglob = bg*16 + brow;
    const double bj = (double)bias[js*16 + jcol];
    const size_t obase = (size_t)bglob*T*F + js*16 + jcol;
    float* outspk = out;
    float* outmem = out + (size_t)64*T*F;

    double syn = 0.0, mem = 0.0, rst = 0.0;
    float xv = (tid < 256) ? x[obase] : 0.f;

    // own-WG gate word: rows 0..3 are the g=0 publish words of waves 0..3
    const int gown = (js>>3)*128 + (js&1)*64 + (lane&3)*4 + ((js>>1)&3);

    __syncthreads();   // W tiles ready (full barrier, once)

    for (int t = 0; t < T; ++t) {
        double h = 0.0;
        if (t > 0) {
            // poll: 4 contiguous A-frag words + 1 own-WG gate word (relaxed sc1)
            const unsigned int tg = (unsigned int)t;   // tag of step t-1 data
            const unsigned int* slot = gbm + (size_t)(((t-1)&3)*4 + bg)*1024;
            const unsigned int* pd = slot + wv*128 + qh*64 + r15*4;
            const unsigned int* pg = slot + gown;
            unsigned int w0, w1, w2, w3, g0;
            do {
                w0 = __hip_atomic_load(pd+0, __ATOMIC_RELAXED, __HIP_MEMORY_SCOPE_AGENT);
                w1 = __hip_atomic_load(pd+1, __ATOMIC_RELAXED, __HIP_MEMORY_SCOPE_AGENT);
                w2 = __hip_atomic_load(pd+2, __ATOMIC_RELAXED, __HIP_MEMORY_SCOPE_AGENT);
                w3 = __hip_atomic_load(pd+3, __ATOMIC_RELAXED, __HIP_MEMORY_SCOPE_AGENT);
                g0 = __hip_atomic_load(pg,   __ATOMIC_RELAXED, __HIP_MEMORY_SCOPE_AGENT);
            } while (__any(((w0>>16)!=tg) | ((w1>>16)!=tg) | ((w2>>16)!=tg) |
                           ((w3>>16)!=tg) | ((g0>>16)!=tg)));

            // MFMA: 4 K-chunks x 4 limbs, exact integer fp32 accumulation
            f32x4 ac0 = {0.f,0.f,0.f,0.f}, ac1 = ac0, ac2 = ac0, ac3 = ac0;
            unsigned int ww[4] = {w0, w1, w2, w3};
            #pragma unroll
            for (int c4 = 0; c4 < 4; ++c4) {
                const int kc = wv*4 + c4;
                unsigned int byt = (ww[c4] >> (ql*8)) & 0xFFu;
                unsigned int d0 = ((byt&1u)  ?0x3F80u:0u) | ((byt&2u)  ?0x3F800000u:0u);
                unsigned int d1 = ((byt&4u)  ?0x3F80u:0u) | ((byt&8u)  ?0x3F800000u:0u);
                unsigned int d2 = ((byt&16u) ?0x3F80u:0u) | ((byt&32u) ?0x3F800000u:0u);
                unsigned int d3 = ((byt&64u) ?0x3F80u:0u) | ((byt&128u)?0x3F800000u:0u);
                i32x4 ai = {(int)d0, (int)d1, (int)d2, (int)d3};
                bf16x8 a = __builtin_bit_cast(bf16x8, ai);
                size_t fo = (size_t)(kc*64 + lane)*4;
                bf16x8 b0 = *(const bf16x8*)(wd0 + fo);
                bf16x8 b1 = *(const bf16x8*)(wd1 + fo);
                bf16x8 b2 = *(const bf16x8*)(wd2 + fo);
                bf16x8 b3 = *(const bf16x8*)(wd3 + fo);
                ac0 = __builtin_amdgcn_mfma_f32_16x16x32_bf16(a, b0, ac0, 0,0,0);
                ac1 = __builtin_amdgcn_mfma_f32_16x16x32_bf16(a, b1, ac1, 0,0,0);
                ac2 = __builtin_amdgcn_mfma_f32_16x16x32_bf16(a, b2, ac2, 0,0,0);
                ac3 = __builtin_amdgcn_mfma_f32_16x16x32_bf16(a, b3, ac3, 0,0,0);
            }
            // limb recombine in fp64 (exact): weight of limb i = 2^(9i-36)
            const double c0 = 1.0/68719476736.0, c1 = 1.0/134217728.0;
            const double c2 = 1.0/262144.0,      c3 = 1.0/512.0;
            #pragma unroll
            for (int r = 0; r < 4; ++r)
                partD[wv*256 + r*64 + lane] =
                    (double)ac0[r]*c0 + (double)ac1[r]*c1 +
                    (double)ac2[r]*c2 + (double)ac3[r]*c3;

            // LDS-only barrier: order partD writes(t) before reads(t) without
            // draining vmcnt (output stores / x prefetch stay in flight).
            __builtin_amdgcn_sched_barrier(0);
            asm volatile("s_waitcnt lgkmcnt(0)\n\ts_barrier" ::: "memory");
            __builtin_amdgcn_sched_barrier(0);

            if (tid < 256) {
                #pragma unroll
                for (int w = 0; w < 8; ++w) h += partD[w*256 + tid];
            }
        }

        // prefetch next x (fire now, consumed next iteration — off the chain)
        float xn = 0.f;
        if (tid < 256 && t + 1 < T) xn = x[obase + (size_t)(t+1)*F];

        if (tid < 256) {
            syn = 0.8*syn + (double)xv + h + bj;
            mem = 0.9*mem + syn - rst;
            bool sp = (mem > 1.0);
            unsigned long long m = __ballot(sp);
            // publish FIRST (critical path): wave wv owns rows 4g+wv, g=lane>>4
            if ((lane & 15) == 0) {
                int g = lane >> 4;
                int row = 4*g + wv;
                unsigned int word = (unsigned int)((m >> (16*g)) & 0xFFFFull);
                unsigned int val = (((unsigned int)(t + 1)) << 16) | word;
                unsigned int* dst = gbm + (size_t)((t&3)*4 + bg)*1024
                                  + (js>>3)*128 + (js&1)*64 + row*4 + ((js>>1)&3);
                __hip_atomic_store(dst, val, __ATOMIC_RELAXED, __HIP_MEMORY_SCOPE_AGENT);
            }
            rst = sp ? 1.0 : 0.0;
            outspk[obase + (size_t)t*F] = sp ? 1.0f : 0.0f;
            outmem[obase + (size_t)t*F] = (float)mem;
        }
        xv = xn;
    }
}

extern "C" void kernel_launch(void* const* d_in, const int* in_sizes, int n_in,
                              void* d_out, int out_size, void* d_ws, size_t ws_size,
                              hipStream_t stream) {
    const float* x    = (const float*)d_in[0];
    const float* W    = (const float*)d_in[1];
    const float* bias = (const float*)d_in[2];
    float* out = (float*)d_out;

    // ws: 4-slot ring of tagged bitmaps [slot 0..3][bg 0..3][1024 uints] = 64KB
    unsigned int* gbm = (unsigned int*)d_ws;

    hipMemsetAsync(d_ws, 0, 65536, stream);  // clear tags every launch (replay-safe)
    hipLaunchKernelGGL(snn_persist_kernel, dim3(256), dim3(512), 0, stream,
                       x, W, bias, out, gbm);
}

// Round 6
// 578.306 us; speedup vs baseline: 2.9644x; 2.9644x over previous
//
#include <hip/hip_runtime.h>

// SNN recurrence, B=64 T=256 F=1024 fp32. 256 persistent WGs (1/CU via
// 146KB LDS) = 64 j-slices (16 output cols, js=bid&63) x 4 batch-groups
// (16 rows, bg=bid>>6). W column-slice in LDS as 4 signed base-512 digit
// limbs (exact in bf16); spk@W.T = 4 bf16 MFMAs per K-chunk with EXACT
// integer fp32 accumulation; limbs recombine in fp64; syn/mem state fp64.
//
// ROUND-3 STRUCTURE (verified 564us) restored verbatim: bg=bid>>6 mapping,
// per-wave 2-load poll of a 128-word slice, wbm LDS staging, consecutive
// 16-word publish (1 cache line/WG/step), two barriers per step.
// Round-6 deltas (all WG-local): (1) LDS-only barriers (no vmcnt drain of
// output stores / x load / publish on the step chain); (2) sbase/mbase
// precompute moves 4 fp64 ops off the post-reduce critical path;
// (3) pairwise-tree partD reduce.
//
// Fence-free tagged-word exchange: word = ((t+1)<<16)|16 spike bits, relaxed
// agent-scope (sc1) stores/loads; 4B store is atomic so data+tag publish
// together. 4-deep slot ring (64KB ws) memset per launch (replay-safe).

#define NT 512

typedef __bf16 bf16x8 __attribute__((ext_vector_type(8)));
typedef float f32x4 __attribute__((ext_vector_type(4)));
typedef int i32x4 __attribute__((ext_vector_type(4)));

static __device__ __forceinline__ unsigned short f2bf(float v) {
    union { float f; unsigned int u; } a; a.f = v;
    unsigned int u = a.u;
    u += 0x7fffu + ((u >> 16) & 1u);   // RNE (exact for small ints)
    return (unsigned short)(u >> 16);
}

// 4 signed base-512 digits of round(w * 2^36); digits in [-256,255], exact in bf16.
static __device__ __forceinline__ void decomp512(float w, int* d) {
    long long v = llround((double)w * 68719476736.0);  // 2^36
    #pragma unroll
    for (int i = 0; i < 4; ++i) {
        int r = (int)(v & 511);
        if (r >= 256) r -= 512;
        d[i] = r;
        v = (v - (long long)r) >> 9;
    }
}

// LDS-only barrier: order LDS ops across waves without draining vmcnt
// (global stores / loads stay in flight across the barrier).
static __device__ __forceinline__ void lds_barrier() {
    __builtin_amdgcn_sched_barrier(0);
    asm volatile("s_waitcnt lgkmcnt(0)\n\ts_barrier" ::: "memory");
    __builtin_amdgcn_sched_barrier(0);
}

__launch_bounds__(NT, 1)
__global__ void snn_persist_kernel(const float* __restrict__ x,
                                   const float* __restrict__ W,
                                   const float* __restrict__ bias,
                                   float* __restrict__ out,
                                   unsigned int* __restrict__ gbm)
{
    constexpr int T = 256, F = 1024;
    const int bid = blockIdx.x;
    const int js  = bid & 63;   // j-slice: output cols js*16 .. js*16+15
    const int bg  = bid >> 6;   // batch group: rows bg*16 .. bg*16+15
    const int tid = threadIdx.x;
    const int lane = tid & 63;
    const int wv   = tid >> 6;  // wave 0..7 (K-split: chunks wv*4..wv*4+3)
    const int q = lane >> 4, r15 = lane & 15;

    // W digit slices, MFMA B-operand order: [kc 0..31][lane 0..63][8 bf16]
    __shared__ __align__(16) unsigned int wd0[32*64*4];
    __shared__ __align__(16) unsigned int wd1[32*64*4];
    __shared__ __align__(16) unsigned int wd2[32*64*4];
    __shared__ __align__(16) unsigned int wd3[32*64*4];
    __shared__ unsigned short wbm[8][128];   // per-wave bitmap slice
    __shared__ double partD[8*256];          // per-wave partial h
    // total LDS = 128KB + 2KB + 16KB = 146KB -> exactly 1 WG/CU

    // ---- init: load W slice, 4-digit split, store in fragment order ----
    // B-frag: lane l supplies B[k=(l>>4)*8+i][n=l&15]; global W[js*16+n][kc*32+(l>>4)*8+i]
    for (int it = 0; it < 4; ++it) {
        int s = tid + NT*it;            // slot 0..2047 = (kc,l)
        int kc = s >> 6, l = s & 63;
        int n = l & 15, qq = l >> 4;
        int f0 = kc*32 + qq*8;
        const float* wr = W + (size_t)(js*16 + n)*F + f0;
        float e[8];
        *(float4*)&e[0] = *(const float4*)(wr);
        *(float4*)&e[4] = *(const float4*)(wr + 4);
        unsigned int pk0[4], pk1[4], pk2[4], pk3[4];
        #pragma unroll
        for (int i = 0; i < 4; ++i) {
            int da[4], db[4];
            decomp512(e[2*i],   da);
            decomp512(e[2*i+1], db);
            pk0[i] = (unsigned int)f2bf((float)da[0]) | ((unsigned int)f2bf((float)db[0]) << 16);
            pk1[i] = (unsigned int)f2bf((float)da[1]) | ((unsigned int)f2bf((float)db[1]) << 16);
            pk2[i] = (unsigned int)f2bf((float)da[2]) | ((unsigned int)f2bf((float)db[2]) << 16);
            pk3[i] = (unsigned int)f2bf((float)da[3]) | ((unsigned int)f2bf((float)db[3]) << 16);
        }
        #pragma unroll
        for (int i = 0; i < 4; ++i) {
            wd0[s*4+i] = pk0[i]; wd1[s*4+i] = pk1[i];
            wd2[s*4+i] = pk2[i]; wd3[s*4+i] = pk3[i];
        }
    }

    // state mapping (tid<256), matching MFMA C layout after the LDS reduce:
    // row b = ((tid>>4)&3)*4 + (tid>>6), col j = tid&15
    const int brow = ((tid >> 4) & 3)*4 + (tid >> 6);
    const int jcol = tid & 15;
    const int bglob = bg*16 + brow;
    const double bj = (double)bias[js*16 + jcol];
    const size_t obase = (size_t)bglob*T*F + js*16 + jcol;
    float* outspk = out;
    float* outmem = out + (size_t)64*T*F;

    double syn = 0.0, mem = 0.0, rst = 0.0;

    __syncthreads();   // W tiles ready (full barrier, once)

    for (int t = 0; t < T; ++t) {
        // x load at top: issued before poll, drained by poll's first vmcnt wait
        float xv = 0.f;
        if (tid < 256) xv = x[obase + (size_t)t*F];

        double h = 0.0;
        double sbase, mbase;
        if (t > 0) {
            // poll own 128-word slice of previous step's tagged bitmap (relaxed sc1)
            const unsigned int tg = (unsigned int)t;   // tag of step t-1 data
            const unsigned int* slot = gbm + (size_t)(((t-1)&3)*4 + bg)*1024;
            const unsigned int* p0 = slot + wv*128 + lane;
            const unsigned int* p1 = p0 + 64;
            unsigned int v0, v1;
            do {
                v0 = __hip_atomic_load(p0, __ATOMIC_RELAXED, __HIP_MEMORY_SCOPE_AGENT);
                v1 = __hip_atomic_load(p1, __ATOMIC_RELAXED, __HIP_MEMORY_SCOPE_AGENT);
            } while (__any(((v0 >> 16) != tg) | ((v1 >> 16) != tg)));
            // stash data halves in own wave's LDS region (same-wave, no barrier)
            wbm[wv][lane]      = (unsigned short)v0;
            wbm[wv][64 + lane] = (unsigned short)v1;

            // off-chain state precompute (independent of h; xv drained by poll)
            sbase = 0.8*syn + (double)xv + bj;
            mbase = 0.9*mem - rst;

            // MFMA: 4 K-chunks x 4 limbs, exact integer fp32 accumulation
            f32x4 ac0 = {0.f,0.f,0.f,0.f}, ac1 = ac0, ac2 = ac0, ac3 = ac0;
            #pragma unroll
            for (int c4 = 0; c4 < 4; ++c4) {
                const int kc = wv*4 + c4;
                // A-frag: lane supplies A[row=r15][k=q*8+i] -> f = kc*32+q*8+i
                unsigned int us = wbm[wv][(2*c4 + (q >> 1))*16 + r15];
                unsigned int byt = (us >> ((q & 1)*8)) & 0xFFu;
                unsigned int d0 = ((byt&1u)  ?0x3F80u:0u) | ((byt&2u)  ?0x3F800000u:0u);
                unsigned int d1 = ((byt&4u)  ?0x3F80u:0u) | ((byt&8u)  ?0x3F800000u:0u);
                unsigned int d2 = ((byt&16u) ?0x3F80u:0u) | ((byt&32u) ?0x3F800000u:0u);
                unsigned int d3 = ((byt&64u) ?0x3F80u:0u) | ((byt&128u)?0x3F800000u:0u);
                i32x4 ai = {(int)d0, (int)d1, (int)d2, (int)d3};
                bf16x8 a = __builtin_bit_cast(bf16x8, ai);
                size_t fo = (size_t)(kc*64 + lane)*4;
                bf16x8 b0 = *(const bf16x8*)(wd0 + fo);
                bf16x8 b1 = *(const bf16x8*)(wd1 + fo);
                bf16x8 b2 = *(const bf16x8*)(wd2 + fo);
                bf16x8 b3 = *(const bf16x8*)(wd3 + fo);
                ac0 = __builtin_amdgcn_mfma_f32_16x16x32_bf16(a, b0, ac0, 0,0,0);
                ac1 = __builtin_amdgcn_mfma_f32_16x16x32_bf16(a, b1, ac1, 0,0,0);
                ac2 = __builtin_amdgcn_mfma_f32_16x16x32_bf16(a, b2, ac2, 0,0,0);
                ac3 = __builtin_amdgcn_mfma_f32_16x16x32_bf16(a, b3, ac3, 0,0,0);
            }
            // limb recombine in fp64 (exact): weight of limb i = 2^(9i-36)
            const double c0 = 1.0/68719476736.0, c1 = 1.0/134217728.0;
            const double c2 = 1.0/262144.0,      c3 = 1.0/512.0;
            #pragma unroll
            for (int r = 0; r < 4; ++r)
                partD[wv*256 + r*64 + lane] =
                    (double)ac0[r]*c0 + (double)ac1[r]*c1 +
                    (double)ac2[r]*c2 + (double)ac3[r]*c3;

            lds_barrier();   // B1: partD writes(t) before reads(t); no vmcnt drain

            if (tid < 256) {
                double s0 = partD[0*256 + tid] + partD[1*256 + tid];
                double s1 = partD[2*256 + tid] + partD[3*256 + tid];
                double s2 = partD[4*256 + tid] + partD[5*256 + tid];
                double s3 = partD[6*256 + tid] + partD[7*256 + tid];
                h = (s0 + s1) + (s2 + s3);
            }
        } else {
            sbase = 0.8*syn + (double)xv + bj;
            mbase = 0.9*mem - rst;
        }

        if (tid < 256) {
            syn = sbase + h;
            mem = mbase + syn;
            bool sp = (mem > 1.0);
            unsigned long long m = __ballot(sp);
            // publish FIRST (critical path): wave wv owns rows 4g+wv, g=lane>>4;
            // 16 consecutive words per WG = one 64B line
            if ((lane & 15) == 0) {
                int g = lane >> 4;
                unsigned int word = (unsigned int)((m >> (16*g)) & 0xFFFFull);
                unsigned int val = (((unsigned int)(t + 1)) << 16) | word;
                unsigned int* dst = gbm + (size_t)((t&3)*4 + bg)*1024 + js*16 + (4*g + wv);
                __hip_atomic_store(dst, val, __ATOMIC_RELAXED, __HIP_MEMORY_SCOPE_AGENT);
            }
            rst = sp ? 1.0 : 0.0;
            outspk[obase + (size_t)t*F] = sp ? 1.0f : 0.0f;
            outmem[obase + (size_t)t*F] = (float)mem;
        }

        lds_barrier();   // B2: partD/wbm reads(t) before writes(t+1); no vmcnt drain
    }
}

extern "C" void kernel_launch(void* const* d_in, const int* in_sizes, int n_in,
                              void* d_out, int out_size, void* d_ws, size_t ws_size,
                              hipStream_t stream) {
    const float* x    = (const float*)d_in[0];
    const float* W    = (const float*)d_in[1];
    const float* bias = (const float*)d_in[2];
    float* out = (float*)d_out;

    // ws: 4-slot ring of tagged bitmaps [slot 0..3][bg 0..3][1024 uints] = 64KB
    unsigned int* gbm = (unsigned int*)d_ws;

    hipMemsetAsync(d_ws, 0, 65536, stream);  // clear tags every launch (replay-safe)
    hipLaunchKernelGGL(snn_persist_kernel, dim3(256), dim3(512), 0, stream,
                       x, W, bias, out, gbm);
}